// Round 15
// baseline (347.395 us; speedup 1.0000x reference)
//
#include <hip/hip_runtime.h>

#define NZ 32768
#define KE 8192
#define DD 256
#define NCHUNK 4
#define CH (KE / NCHUNK)     // 2048 codes per chunk
#define NSLICE (NCHUNK * 4)  // 16 partial slices (4 wc quarters per chunk)
#define ITERS ((CH / 128) * 8)
#define THR_GAP 0.05f
#define BIASF 128.0f

typedef __attribute__((ext_vector_type(8))) _Float16 f16x8;
typedef __attribute__((ext_vector_type(4))) float f32x4;
typedef unsigned int uint32;

// ---------------------------------------------------------------- utilities

__device__ __forceinline__ float wave_reduce_sum(float v) {
#pragma unroll
  for (int m = 32; m >= 1; m >>= 1) v += __shfl_xor(v, m, 64);
  return v;
}

// ---------------------------------------------------------------- prologue:
// r28: emb-only (fp32->fp16 + row-square) + sum(ema_cluster_size) + o_loss
// zero. The z-half of the old prep is FUSED into mfma_argmin (A staged from
// fp32 with in-register cvt, bit-identical RTN) and combine (z2 computed
// inline from the zv row it already loads). Grid 10241 -> 2049 blocks.
__global__ void prep_kernel(const float* __restrict__ emb, unsigned short* __restrict__ e_dst,
                            float* __restrict__ e_sq, const float* __restrict__ ema_cs,
                            float* __restrict__ sema_out, float* __restrict__ o_loss) {
  const int gb = blockIdx.x;
  if (gb < KE / 4) {
    const int row = gb * 4 + (threadIdx.x >> 6);
    const int lane = threadIdx.x & 63;
    const float4 v = *reinterpret_cast<const float4*>(emb + (size_t)row * DD + lane * 4);
    alignas(8) _Float16 hv[4] = {(_Float16)v.x, (_Float16)v.y, (_Float16)v.z, (_Float16)v.w};
    *reinterpret_cast<uint2*>(e_dst + (size_t)row * DD + lane * 4) =
        *reinterpret_cast<const uint2*>(hv);
    float s = (v.x * v.x + v.y * v.y) + (v.z * v.z + v.w * v.w);
    s = wave_reduce_sum(s);
    if (lane == 0) e_sq[row] = s;
  } else {
    __shared__ float red[256];
    float s = 0.f;
    for (int i = threadIdx.x; i < KE; i += 256) s += ema_cs[i];
    red[threadIdx.x] = s;
    __syncthreads();
    for (int off = 128; off >= 1; off >>= 1) {
      if (threadIdx.x < off) red[threadIdx.x] += red[threadIdx.x + off];
      __syncthreads();
    }
    if (threadIdx.x == 0) {
      sema_out[0] = red[0];
      o_loss[0] = 0.f;
    }
  }
}

// ---------------------------------------------------------------- MFMA argmin GEMM
// r28 = r27 with the A-tile staged DIRECTLY from fp32 z: per thread per ki,
// 2x float4 loads + in-register fp32->fp16 cvt (same RTN as the old prep's
// cast -> bit-identical A tile) + the same uint4 LDS write. The z-half of
// prep (48 MB of HBM traffic + a 8192-block launch chunk) disappears.
// Everything else r27-verbatim: counted-vmcnt DMA B staging (16 bufs, 4
// groups, vmcnt(4) barriers), e2/BIAS folded into acc init (r26), branchless
// packed-key MAX top-2 (r24/r26).

#define LSTR 32
#define NWIN (ITERS / 4)  // 32 windows of 4 K-steps

// A staging overlay: slice ki occupies exactly ldsB[ki] (128 rows x 32 shorts)
#define LDSA(ki, r) (&ldsB[ki][r][0])

// one global_load_lds per wave per step: 16 rows x 64B, linear LDS dest,
// pre-swizzled global source (r25/r27-proven).
#define STAGEB(buf, itv)                                                        \
  {                                                                             \
    const int kb_ = ((itv) & 7) * 32;                                           \
    const size_t bo_ = (size_t)((itv) >> 3) * 128 * DD + kb_;                   \
    __builtin_amdgcn_global_load_lds((const uint32*)(ef + bsw + bo_),           \
                                     (uint32*)&ldsB[buf][wid * 16][0], 16, 0, 0); \
  }

// stage window ws (4 steps) into buf group SG (literal)
#define STAGEW(SG, ws)                                                          \
  {                                                                             \
    const int s0_ = (ws) * 4;                                                   \
    STAGEB((SG)*4 + 0, s0_ + 0)                                                 \
    STAGEB((SG)*4 + 1, s0_ + 1)                                                 \
    STAGEB((SG)*4 + 2, s0_ + 2)                                                 \
    STAGEB((SG)*4 + 3, s0_ + 3)                                                 \
  }

#define VBAR4                                                  \
  asm volatile("s_waitcnt vmcnt(4)" ::: "memory");             \
  __builtin_amdgcn_s_barrier();                                \
  __builtin_amdgcn_sched_barrier(0);

#define VBAR0                                                  \
  asm volatile("s_waitcnt vmcnt(0)" ::: "memory");             \
  __builtin_amdgcn_s_barrier();                                \
  __builtin_amdgcn_sched_barrier(0);

__launch_bounds__(512, 1)
__global__ void mfma_argmin_kernel(const float* __restrict__ zfp,
                                   const unsigned short* __restrict__ ef,
                                   const float* __restrict__ e2,
                                   float4* __restrict__ pt) {
  __shared__ unsigned short ldsB[16][128][LSTR];  // 131072 B: 16 B-bufs; 0..7 double as A staging
  __shared__ float ldsE2[CH];                     // 8192 B: 128 - e2/2, pre-transformed
  const int bid = blockIdx.x;
  const int c = (bid & 7) >> 1;                    // chunk 0..3 (2 XCDs/chunk)
  const int mblk = ((bid >> 3) << 1) | (bid & 1);  // 0..255
  const int row0 = mblk * 128;
  const int cbase = c * CH;
  const int tid = threadIdx.x;
  const int wid = tid >> 6, lane = tid & 63;
  const int wr = wid >> 2, wc = wid & 3;           // 2 x 4 wave grid
  const int lg = lane >> 4, l15 = lane & 15;

  const int ur = tid >> 2;                         // 0..127
  const int usw = (((tid & 3) ^ ((ur >> 1) & 3)) << 3);
  const int csw = ((lg ^ ((l15 >> 1) & 3)) << 3);
  const size_t aoff0 = (size_t)(row0 + ur) * DD + (tid & 3) * 8;  // fp32 elem index
  // B DMA source: row = ur, source chunk = (lane&3) ^ ((lane>>3)&3)
  const size_t bsw = (size_t)(cbase + ur) * DD + ((lane & 3) ^ ((lane >> 3) & 3)) * 8;

  // packed top-2 MAX trackers: key = (float_bits(z.e - e2/2 + 128) & ~63) | meta
  uint32 k1[4][4], k2[4][4];
#pragma unroll
  for (int i = 0; i < 4; ++i)
#pragma unroll
    for (int r = 0; r < 4; ++r) { k1[i][r] = 0u; k2[i][r] = 0u; }

  f32x4 acc[4][2];
  f16x8 areg[8][4];  // 128 VGPR: this wave's full A panel (64 rows x D=256)

  // prologue: stage e2 (pre-transformed) + A (fp32 -> f16 in-register) into LDS
  for (int i = tid; i < CH; i += 512) ldsE2[i] = BIASF - 0.5f * e2[cbase + i];
#pragma unroll
  for (int ki = 0; ki < 8; ++ki) {
    const float4 va = *reinterpret_cast<const float4*>(zfp + aoff0 + ki * 32);
    const float4 vb = *reinterpret_cast<const float4*>(zfp + aoff0 + ki * 32 + 4);
    alignas(16) _Float16 hv[8] = {(_Float16)va.x, (_Float16)va.y, (_Float16)va.z,
                                  (_Float16)va.w, (_Float16)vb.x, (_Float16)vb.y,
                                  (_Float16)vb.z, (_Float16)vb.w};
    *reinterpret_cast<uint4*>(LDSA(ki, ur) + usw) = *reinterpret_cast<const uint4*>(hv);
  }
  __syncthreads();
  // A fragments -> registers
#pragma unroll
  for (int ki = 0; ki < 8; ++ki)
#pragma unroll
    for (int x = 0; x < 4; ++x)
      areg[ki][x] =
          *reinterpret_cast<const f16x8*>(LDSA(ki, wr * 64 + x * 16 + l15) + csw);
  __syncthreads();  // all waves' areg reads complete before DMA overwrites region
  // DMA windows 0,1 -> groups 0,1; vmcnt(4) completes window 0
  STAGEW(0, 0)
  STAGEW(1, 1)
  VBAR4

#define COMPUTE(buf, kil, tl)                                                           \
  {                                                                                     \
    if ((kil) == 0) {                                                                   \
      const int e2o_ = ((tl) << 7) + wc * 32 + l15;                                     \
      const float e0_ = ldsE2[e2o_];                                                    \
      const float e1_ = ldsE2[e2o_ + 16];                                               \
      _Pragma("unroll") for (int i = 0; i < 4; ++i) {                                   \
        acc[i][0] = (f32x4)(e0_);                                                       \
        acc[i][1] = (f32x4)(e1_);                                                       \
      }                                                                                 \
    }                                                                                   \
    f16x8 bh[2];                                                                        \
    _Pragma("unroll") for (int x = 0; x < 2; ++x)                                       \
      bh[x] = *reinterpret_cast<const f16x8*>(&ldsB[buf][wc * 32 + x * 16 + l15][csw]); \
    _Pragma("unroll") for (int i = 0; i < 4; ++i)                                       \
        _Pragma("unroll") for (int j = 0; j < 2; ++j)                                   \
            acc[i][j] = __builtin_amdgcn_mfma_f32_16x16x32_f16(areg[kil][i], bh[j], acc[i][j], 0, 0, 0); \
    if ((kil) == 7) {                                                                   \
      const uint32 tb_ = (uint32)((tl) << 2);                                           \
      _Pragma("unroll") for (int j = 0; j < 2; ++j) {                                   \
        const uint32 meta = tb_ | (uint32)j;                                            \
        _Pragma("unroll") for (int i = 0; i < 4; ++i)                                   \
            _Pragma("unroll") for (int r = 0; r < 4; ++r) {                             \
          const uint32 key = (__float_as_uint(acc[i][j][r]) & 0xFFFFFFC0u) | meta;      \
          const uint32 t = min(k1[i][r], key);                                          \
          k1[i][r] = max(k1[i][r], key);                                                \
          k2[i][r] = max(k2[i][r], t);                                                  \
        }                                                                               \
      }                                                                                 \
    }                                                                                   \
  }

// window wv: stage window wv+2 into group SG, compute group G, counted barrier.
// G = wv&3, SG = (wv+2)&3, P = wv&1 (all passed as literals); tile = wv>>1.
#define WINDOW(G, SG, wv, P)                                                \
  STAGEW(SG, (wv) + 2)                                                      \
  {                                                                         \
    const int tl_ = (wv) >> 1;                                              \
    COMPUTE((G)*4 + 0, (P)*4 + 0, tl_)                                      \
    COMPUTE((G)*4 + 1, (P)*4 + 1, tl_)                                      \
    COMPUTE((G)*4 + 2, (P)*4 + 2, tl_)                                      \
    COMPUTE((G)*4 + 3, (P)*4 + 3, tl_)                                      \
  }                                                                         \
  VBAR4

  // main loop: windows 0..27 (stages up to window 29)
  for (int W = 0; W < 28; W += 4) {
    WINDOW(0, 2, W + 0, 0)
    WINDOW(1, 3, W + 1, 1)
    WINDOW(2, 0, W + 2, 0)
    WINDOW(3, 1, W + 3, 1)
  }
  // windows 28,29: stage windows 30,31
  WINDOW(0, 2, 28, 0)
  WINDOW(1, 3, 29, 1)
  // window 30 (group 2, tile 15, ki 0..3): no stage; full drain for window 31
  COMPUTE(8, 0, 15)
  COMPUTE(9, 1, 15)
  COMPUTE(10, 2, 15)
  COMPUTE(11, 3, 15)
  VBAR0
  // window 31 (group 3, tile 15, ki 4..7)
  COMPUTE(12, 4, 15)
  COMPUTE(13, 5, 15)
  COMPUTE(14, 6, 15)
  COMPUTE(15, 7, 15)

  // decode packed MAX-keys back to (float distance value, 16-bit code) pairs:
  // tracked q = z.e - e2/2 + 128 ; v = e2 - 2 z.e = 256 - 2q
  float bv1[4][4], bv2[4][4];
  uint32 bpi[4][4];
  const uint32 cb_ = (uint32)(cbase + wc * 32 + l15);
#pragma unroll
  for (int i = 0; i < 4; ++i)
#pragma unroll
    for (int r = 0; r < 4; ++r) {
      const uint32 a1 = k1[i][r], a2 = k2[i][r];
      bv1[i][r] = 2.f * BIASF - 2.f * __uint_as_float(a1 & 0xFFFFFFC0u);
      bv2[i][r] = 2.f * BIASF - 2.f * __uint_as_float(a2 & 0xFFFFFFC0u);
      const uint32 c1 = cb_ + ((a1 & 60u) >> 2) * 128u + ((a1 & 3u) << 4);
      const uint32 c2 = cb_ + ((a2 & 60u) >> 2) * 128u + ((a2 & 3u) << 4);
      bpi[i][r] = c1 | (c2 << 16);
    }

  // cross-lane top-2 merge within 16-lane column groups (float-domain, unchanged)
#pragma unroll
  for (int m = 1; m <= 8; m <<= 1) {
#pragma unroll
    for (int i = 0; i < 4; ++i)
#pragma unroll
      for (int r = 0; r < 4; ++r) {
        const float ov1 = __shfl_xor(bv1[i][r], m, 64);
        const float ov2 = __shfl_xor(bv2[i][r], m, 64);
        const uint32 op = (uint32)__shfl_xor((int)bpi[i][r], m, 64);
        const uint32 ai1 = bpi[i][r] & 0xFFFFu, oi1 = op & 0xFFFFu;
        const bool ol = (ov1 < bv1[i][r]) || (ov1 == bv1[i][r] && oi1 < ai1);
        const float w1 = ol ? ov1 : bv1[i][r];
        const uint32 wi1 = ol ? oi1 : ai1;
        const float w2 = ol ? ov2 : bv2[i][r];
        const uint32 wi2 = ol ? (op >> 16) : (bpi[i][r] >> 16);
        const float l1 = ol ? bv1[i][r] : ov1;
        const uint32 li1 = ol ? ai1 : oi1;
        const bool s2 = (l1 < w2) || (l1 == w2 && li1 < wi2);
        bv1[i][r] = w1;
        bv2[i][r] = s2 ? l1 : w2;
        bpi[i][r] = wi1 | ((s2 ? li1 : wi2) << 16);
      }
  }
  if (l15 == 0) {
    const int slice = c * 4 + wc;
#pragma unroll
    for (int i = 0; i < 4; ++i)
#pragma unroll
      for (int r = 0; r < 4; ++r) {
        const int row = row0 + wr * 64 + i * 16 + lg * 4 + r;
        pt[(size_t)slice * NZ + row] =
            make_float4(bv1[i][r], bv2[i][r], __uint_as_float(bpi[i][r]), 0.f);
      }
  }
}

// ---------------------------------------------------------------- combine + exact fixup + quantize + loss
// 16 slices (lane&15 groups), 32 candidates. r28: z2 computed inline from zv
// (same op order as old prep: 4 products, pairwise adds, same butterfly --
// bit-identical).
__global__ void combine_kernel(const float* __restrict__ z, const float* __restrict__ emb,
                               const float* __restrict__ e2,
                               const float4* __restrict__ pt, float* __restrict__ oidx_f,
                               int* __restrict__ oidx_i, float* __restrict__ oq,
                               float* __restrict__ oloss) {
  const int row = blockIdx.x * 4 + (threadIdx.x >> 6);
  const int lane = threadIdx.x & 63;
  const int wid = threadIdx.x >> 6;
  const float4 p = pt[(size_t)(lane & 15) * NZ + row];
  const float v1 = p.x, v2 = p.y;
  const uint32 pk = __float_as_uint(p.z);
  float m = v1;
#pragma unroll
  for (int s = 1; s <= 8; s <<= 1) m = fminf(m, __shfl_xor(m, s, 64));

  const float4 zv = *reinterpret_cast<const float4*>(z + (size_t)row * DD + lane * 4);
  float z2r = (zv.x * zv.x + zv.y * zv.y) + (zv.z * zv.z + zv.w * zv.w);
  z2r = wave_reduce_sum(z2r);
  float bestd = 3.4e38f;
  int besti = KE;
#pragma unroll 1
  for (int cnum = 0; cnum < 32; ++cnum) {
    const int src = (lane & 48) | (cnum >> 1);
    const float vc = __shfl((cnum & 1) ? v2 : v1, src, 64);
    const uint32 pkc = (uint32)__shfl((int)pk, src, 64);
    const int idxc = (cnum & 1) ? (int)(pkc >> 16) : (int)(pkc & 0xFFFFu);
    if (vc < m + THR_GAP) {
      const float4 ev = *reinterpret_cast<const float4*>(emb + (size_t)idxc * DD + lane * 4);
      float s = (zv.x * ev.x + zv.y * ev.y) + (zv.z * ev.z + zv.w * ev.w);
      s = wave_reduce_sum(s);
      const float d = (z2r - 2.f * s) + e2[idxc];
      if (d < bestd || (d == bestd && idxc < besti)) { bestd = d; besti = idxc; }
    }
  }
  if (lane == 0) {
    oidx_f[row] = (float)besti;
    oidx_i[row] = besti;
  }
  // fused quantize + loss (quantized_st == emb[besti] numerically)
  const float4 qv = *reinterpret_cast<const float4*>(emb + (size_t)besti * DD + lane * 4);
  *reinterpret_cast<float4*>(oq + (size_t)row * DD + lane * 4) = qv;
  const float dx = zv.x - qv.x, dy = zv.y - qv.y, dz = zv.z - qv.z, dw = zv.w - qv.w;
  float s = (dx * dx + dy * dy) + (dz * dz + dw * dw);
  s = wave_reduce_sum(s);
  __shared__ float red[4];
  if (lane == 0) red[wid] = s;
  __syncthreads();
  if (threadIdx.x == 0) {
    const float t = (red[0] + red[1]) + (red[2] + red[3]);
    atomicAdd(oloss, t * (1.25f / ((float)NZ * (float)DD)));
  }
}

// ---------------------------------------------------------------- per-code EMA (8 codes/block)
__global__ void perk_kernel(const float* __restrict__ z, const float* __restrict__ ema_cs,
                            const float* __restrict__ ema_es, const int* __restrict__ usage,
                            const int* __restrict__ idx, const float* __restrict__ sema,
                            float* __restrict__ o_emb, float* __restrict__ o_cs,
                            float* __restrict__ o_es, float* __restrict__ o_us) {
  const int k0 = blockIdx.x * 8;
  const int tid = threadIdx.x;
  __shared__ int cnt;
  __shared__ int cnt8[8];
  __shared__ int stot[8];
  __shared__ int rows[2048];
  float acc[8];
#pragma unroll
  for (int q = 0; q < 8; ++q) acc[q] = 0.f;
  if (tid < 8) stot[tid] = 0;
  for (int base = 0; base < NZ; base += 2048) {
    if (tid == 0) cnt = 0;
    if (tid < 8) cnt8[tid] = 0;
    __syncthreads();
#pragma unroll
    for (int t = 0; t < 2048; t += 256) {
      const int r = base + t + tid;
      const int q = idx[r] - k0;
      if ((unsigned)q < 8u) {
        rows[atomicAdd(&cnt, 1)] = (r << 3) | q;
        atomicAdd(&cnt8[q], 1);
      }
    }
    __syncthreads();
    const int cq = cnt;
    if (tid < 8) stot[tid] += cnt8[tid];
    for (int m = 0; m < cq; ++m) {
      const int rr = rows[m];
      const float v = z[(size_t)(rr >> 3) * DD + tid];
      const int q = rr & 7;
#pragma unroll
      for (int qq = 0; qq < 8; ++qq)
        if (qq == q) acc[qq] += v;
    }
    __syncthreads();
  }
  const float n = 0.99f * sema[0] + 0.01f * (float)NZ;
  const float dn = n + (float)KE * 1e-5f;
#pragma unroll
  for (int q = 0; q < 8; ++q) {
    const float ncs = 0.99f * ema_cs[k0 + q] + 0.01f * (float)stot[q];
    const float nes = 0.99f * ema_es[(size_t)(k0 + q) * DD + tid] + 0.01f * acc[q];
    o_es[(size_t)(k0 + q) * DD + tid] = nes;
    o_emb[(size_t)(k0 + q) * DD + tid] = nes / ((ncs + 1e-5f) / dn * n);
  }
  if (tid < 8) {
    o_cs[k0 + tid] = 0.99f * ema_cs[k0 + tid] + 0.01f * (float)stot[tid];
    o_us[k0 + tid] = (float)(usage[k0 + tid] + stot[tid]);
  }
}

// ---------------------------------------------------------------- launch

extern "C" void kernel_launch(void* const* d_in, const int* in_sizes, int n_in,
                              void* d_out, int out_size, void* d_ws, size_t ws_size,
                              hipStream_t stream) {
  const float* z = (const float*)d_in[0];
  const float* emb = (const float*)d_in[1];
  const float* ema_cs = (const float*)d_in[2];
  const float* ema_es = (const float*)d_in[3];
  const int* usage = (const int*)d_in[4];

  float* out = (float*)d_out;
  float* o_idx = out;
  float* o_q = o_idx + NZ;
  float* o_loss = o_q + (size_t)NZ * DD;
  float* o_emb = o_loss + 1;
  float* o_cs = o_emb + (size_t)KE * DD;
  float* o_es = o_cs + KE;
  float* o_us = o_es + (size_t)KE * DD;

  char* w = (char*)d_ws;
  size_t off = 0;
  auto alloc = [&](size_t bytes) -> char* {
    char* r = w + off;
    off = (off + bytes + 255) & ~(size_t)255;
    return r;
  };
  float* ws_e2 = (float*)alloc(KE * 4);
  float* ws_sema = (float*)alloc(256);
  int* ws_idx = (int*)alloc(NZ * 4);
  float4* ws_pt = (float4*)alloc((size_t)NSLICE * NZ * 16);
  unsigned short* e_f16 = (unsigned short*)alloc((size_t)KE * DD * 2);
  (void)ws_size;

  prep_kernel<<<(KE / 4) + 1, 256, 0, stream>>>(emb, e_f16, ws_e2, ema_cs, ws_sema,
                                                o_loss);

  mfma_argmin_kernel<<<(NZ / 128) * NCHUNK, 512, 0, stream>>>(z, e_f16, ws_e2, ws_pt);
  combine_kernel<<<NZ / 4, 256, 0, stream>>>(z, emb, ws_e2, ws_pt, o_idx, ws_idx,
                                             o_q, o_loss);
  perk_kernel<<<KE / 8, 256, 0, stream>>>(z, ema_cs, ema_es, usage, ws_idx, ws_sema,
                                          o_emb, o_cs, o_es, o_us);
}

// Round 16
// 343.079 us; speedup vs baseline: 1.0126x; 1.0126x over previous
//
#include <hip/hip_runtime.h>

#define NZ 32768
#define KE 8192
#define DD 256
#define NCHUNK 4
#define CH (KE / NCHUNK)     // 2048 codes per chunk
#define NSLICE (NCHUNK * 4)  // 16 partial slices (4 wc quarters per chunk)
#define ITERS ((CH / 128) * 8)
#define THR_GAP 0.05f
#define BIASF 128.0f

typedef __attribute__((ext_vector_type(8))) _Float16 f16x8;
typedef __attribute__((ext_vector_type(4))) float f32x4;
typedef unsigned int uint32;

// ---------------------------------------------------------------- utilities

__device__ __forceinline__ float wave_reduce_sum(float v) {
#pragma unroll
  for (int m = 32; m >= 1; m >>= 1) v += __shfl_xor(v, m, 64);
  return v;
}

// ---------------------------------------------------------------- fused prologue:
// r29: emb fp32->fp16 + row-square; z fp32->fp16 (NO z2 -- combine computes it
// inline, r28's good half); sum(ema_cluster_size); o_loss zero. r28's fp32
// A-staging inside argmin regressed (doubled prologue bytes, +9.5us) -- the
// f16 z conversion belongs here where it streams at full BW once.
__global__ void prep_kernel(const float* __restrict__ emb, unsigned short* __restrict__ e_dst,
                            float* __restrict__ e_sq, const float* __restrict__ z,
                            unsigned short* __restrict__ z_dst,
                            const float* __restrict__ ema_cs, float* __restrict__ sema_out,
                            float* __restrict__ o_loss) {
  const int gb = blockIdx.x;
  if (gb < KE / 4) {
    const int row = gb * 4 + (threadIdx.x >> 6);
    const int lane = threadIdx.x & 63;
    const float4 v = *reinterpret_cast<const float4*>(emb + (size_t)row * DD + lane * 4);
    alignas(8) _Float16 hv[4] = {(_Float16)v.x, (_Float16)v.y, (_Float16)v.z, (_Float16)v.w};
    *reinterpret_cast<uint2*>(e_dst + (size_t)row * DD + lane * 4) =
        *reinterpret_cast<const uint2*>(hv);
    float s = (v.x * v.x + v.y * v.y) + (v.z * v.z + v.w * v.w);
    s = wave_reduce_sum(s);
    if (lane == 0) e_sq[row] = s;
  } else if (gb < (KE / 4) + (NZ / 4)) {
    const int row = (gb - KE / 4) * 4 + (threadIdx.x >> 6);
    const int lane = threadIdx.x & 63;
    const float4 v = *reinterpret_cast<const float4*>(z + (size_t)row * DD + lane * 4);
    alignas(8) _Float16 hv[4] = {(_Float16)v.x, (_Float16)v.y, (_Float16)v.z, (_Float16)v.w};
    *reinterpret_cast<uint2*>(z_dst + (size_t)row * DD + lane * 4) =
        *reinterpret_cast<const uint2*>(hv);
  } else {
    __shared__ float red[256];
    float s = 0.f;
    for (int i = threadIdx.x; i < KE; i += 256) s += ema_cs[i];
    red[threadIdx.x] = s;
    __syncthreads();
    for (int off = 128; off >= 1; off >>= 1) {
      if (threadIdx.x < off) red[threadIdx.x] += red[threadIdx.x + off];
      __syncthreads();
    }
    if (threadIdx.x == 0) {
      sema_out[0] = red[0];
      o_loss[0] = 0.f;
    }
  }
}

// ---------------------------------------------------------------- MFMA argmin GEMM
// r29 = r27 VERBATIM (proven 181.5 us): f16 A staged from z_f16 (128 KB
// prologue), counted-vmcnt DMA B staging (16 bufs, 4 groups of 4; window w
// computes group w&3 while DMA-staging window w+2; barrier = vmcnt(4) +
// s_barrier + sched_barrier(0) -- completes window w+1 without draining
// w+2's DMAs), e2/BIAS folded into acc init (r26), branchless packed-key
// MAX top-2 (r24/r26). r28's fp32 A-staging reverted (FETCH 37->82 MB,
// +9.5us prologue latency).

#define LSTR 32
#define NWIN (ITERS / 4)  // 32 windows of 4 K-steps

// A staging overlay: slice ki occupies exactly ldsB[ki] (128 rows x 32 shorts)
#define LDSA(ki, r) (&ldsB[ki][r][0])

// one global_load_lds per wave per step: 16 rows x 64B, linear LDS dest,
// pre-swizzled global source (r25/r27-proven).
#define STAGEB(buf, itv)                                                        \
  {                                                                             \
    const int kb_ = ((itv) & 7) * 32;                                           \
    const size_t bo_ = (size_t)((itv) >> 3) * 128 * DD + kb_;                   \
    __builtin_amdgcn_global_load_lds((const uint32*)(ef + bsw + bo_),           \
                                     (uint32*)&ldsB[buf][wid * 16][0], 16, 0, 0); \
  }

// stage window ws (4 steps) into buf group SG (literal)
#define STAGEW(SG, ws)                                                          \
  {                                                                             \
    const int s0_ = (ws) * 4;                                                   \
    STAGEB((SG)*4 + 0, s0_ + 0)                                                 \
    STAGEB((SG)*4 + 1, s0_ + 1)                                                 \
    STAGEB((SG)*4 + 2, s0_ + 2)                                                 \
    STAGEB((SG)*4 + 3, s0_ + 3)                                                 \
  }

#define VBAR4                                                  \
  asm volatile("s_waitcnt vmcnt(4)" ::: "memory");             \
  __builtin_amdgcn_s_barrier();                                \
  __builtin_amdgcn_sched_barrier(0);

#define VBAR0                                                  \
  asm volatile("s_waitcnt vmcnt(0)" ::: "memory");             \
  __builtin_amdgcn_s_barrier();                                \
  __builtin_amdgcn_sched_barrier(0);

__launch_bounds__(512, 1)
__global__ void mfma_argmin_kernel(const unsigned short* __restrict__ zf,
                                   const unsigned short* __restrict__ ef,
                                   const float* __restrict__ e2,
                                   float4* __restrict__ pt) {
  __shared__ unsigned short ldsB[16][128][LSTR];  // 131072 B: 16 B-bufs; 0..7 double as A staging
  __shared__ float ldsE2[CH];                     // 8192 B: 128 - e2/2, pre-transformed
  const int bid = blockIdx.x;
  const int c = (bid & 7) >> 1;                    // chunk 0..3 (2 XCDs/chunk)
  const int mblk = ((bid >> 3) << 1) | (bid & 1);  // 0..255
  const int row0 = mblk * 128;
  const int cbase = c * CH;
  const int tid = threadIdx.x;
  const int wid = tid >> 6, lane = tid & 63;
  const int wr = wid >> 2, wc = wid & 3;           // 2 x 4 wave grid
  const int lg = lane >> 4, l15 = lane & 15;

  const int ur = tid >> 2;                         // 0..127
  const int usw = (((tid & 3) ^ ((ur >> 1) & 3)) << 3);
  const int csw = ((lg ^ ((l15 >> 1) & 3)) << 3);
  const size_t aoff0 = (size_t)(row0 + ur) * DD + (tid & 3) * 8;
  // B DMA source: row = ur, source chunk = (lane&3) ^ ((lane>>3)&3)
  const size_t bsw = (size_t)(cbase + ur) * DD + ((lane & 3) ^ ((lane >> 3) & 3)) * 8;

  // packed top-2 MAX trackers: key = (float_bits(z.e - e2/2 + 128) & ~63) | meta
  uint32 k1[4][4], k2[4][4];
#pragma unroll
  for (int i = 0; i < 4; ++i)
#pragma unroll
    for (int r = 0; r < 4; ++r) { k1[i][r] = 0u; k2[i][r] = 0u; }

  f32x4 acc[4][2];
  f16x8 areg[8][4];  // 128 VGPR: this wave's full A panel (64 rows x D=256)

  // prologue: stage e2 (pre-transformed) + A into LDS
  for (int i = tid; i < CH; i += 512) ldsE2[i] = BIASF - 0.5f * e2[cbase + i];
#pragma unroll
  for (int ki = 0; ki < 8; ++ki) {
    const uint4 va0 = *reinterpret_cast<const uint4*>(zf + aoff0 + ki * 32);
    *reinterpret_cast<uint4*>(LDSA(ki, ur) + usw) = va0;
  }
  __syncthreads();
  // A fragments -> registers
#pragma unroll
  for (int ki = 0; ki < 8; ++ki)
#pragma unroll
    for (int x = 0; x < 4; ++x)
      areg[ki][x] =
          *reinterpret_cast<const f16x8*>(LDSA(ki, wr * 64 + x * 16 + l15) + csw);
  __syncthreads();  // all waves' areg reads complete before DMA overwrites region
  // DMA windows 0,1 -> groups 0,1; vmcnt(4) completes window 0
  STAGEW(0, 0)
  STAGEW(1, 1)
  VBAR4

#define COMPUTE(buf, kil, tl)                                                           \
  {                                                                                     \
    if ((kil) == 0) {                                                                   \
      const int e2o_ = ((tl) << 7) + wc * 32 + l15;                                     \
      const float e0_ = ldsE2[e2o_];                                                    \
      const float e1_ = ldsE2[e2o_ + 16];                                               \
      _Pragma("unroll") for (int i = 0; i < 4; ++i) {                                   \
        acc[i][0] = (f32x4)(e0_);                                                       \
        acc[i][1] = (f32x4)(e1_);                                                       \
      }                                                                                 \
    }                                                                                   \
    f16x8 bh[2];                                                                        \
    _Pragma("unroll") for (int x = 0; x < 2; ++x)                                       \
      bh[x] = *reinterpret_cast<const f16x8*>(&ldsB[buf][wc * 32 + x * 16 + l15][csw]); \
    _Pragma("unroll") for (int i = 0; i < 4; ++i)                                       \
        _Pragma("unroll") for (int j = 0; j < 2; ++j)                                   \
            acc[i][j] = __builtin_amdgcn_mfma_f32_16x16x32_f16(areg[kil][i], bh[j], acc[i][j], 0, 0, 0); \
    if ((kil) == 7) {                                                                   \
      const uint32 tb_ = (uint32)((tl) << 2);                                           \
      _Pragma("unroll") for (int j = 0; j < 2; ++j) {                                   \
        const uint32 meta = tb_ | (uint32)j;                                            \
        _Pragma("unroll") for (int i = 0; i < 4; ++i)                                   \
            _Pragma("unroll") for (int r = 0; r < 4; ++r) {                             \
          const uint32 key = (__float_as_uint(acc[i][j][r]) & 0xFFFFFFC0u) | meta;      \
          const uint32 t = min(k1[i][r], key);                                          \
          k1[i][r] = max(k1[i][r], key);                                                \
          k2[i][r] = max(k2[i][r], t);                                                  \
        }                                                                               \
      }                                                                                 \
    }                                                                                   \
  }

// window wv: stage window wv+2 into group SG, compute group G, counted barrier.
// G = wv&3, SG = (wv+2)&3, P = wv&1 (all passed as literals); tile = wv>>1.
#define WINDOW(G, SG, wv, P)                                                \
  STAGEW(SG, (wv) + 2)                                                      \
  {                                                                         \
    const int tl_ = (wv) >> 1;                                              \
    COMPUTE((G)*4 + 0, (P)*4 + 0, tl_)                                      \
    COMPUTE((G)*4 + 1, (P)*4 + 1, tl_)                                      \
    COMPUTE((G)*4 + 2, (P)*4 + 2, tl_)                                      \
    COMPUTE((G)*4 + 3, (P)*4 + 3, tl_)                                      \
  }                                                                         \
  VBAR4

  // main loop: windows 0..27 (stages up to window 29)
  for (int W = 0; W < 28; W += 4) {
    WINDOW(0, 2, W + 0, 0)
    WINDOW(1, 3, W + 1, 1)
    WINDOW(2, 0, W + 2, 0)
    WINDOW(3, 1, W + 3, 1)
  }
  // windows 28,29: stage windows 30,31
  WINDOW(0, 2, 28, 0)
  WINDOW(1, 3, 29, 1)
  // window 30 (group 2, tile 15, ki 0..3): no stage; full drain for window 31
  COMPUTE(8, 0, 15)
  COMPUTE(9, 1, 15)
  COMPUTE(10, 2, 15)
  COMPUTE(11, 3, 15)
  VBAR0
  // window 31 (group 3, tile 15, ki 4..7)
  COMPUTE(12, 4, 15)
  COMPUTE(13, 5, 15)
  COMPUTE(14, 6, 15)
  COMPUTE(15, 7, 15)

  // decode packed MAX-keys back to (float distance value, 16-bit code) pairs:
  // tracked q = z.e - e2/2 + 128 ; v = e2 - 2 z.e = 256 - 2q
  float bv1[4][4], bv2[4][4];
  uint32 bpi[4][4];
  const uint32 cb_ = (uint32)(cbase + wc * 32 + l15);
#pragma unroll
  for (int i = 0; i < 4; ++i)
#pragma unroll
    for (int r = 0; r < 4; ++r) {
      const uint32 a1 = k1[i][r], a2 = k2[i][r];
      bv1[i][r] = 2.f * BIASF - 2.f * __uint_as_float(a1 & 0xFFFFFFC0u);
      bv2[i][r] = 2.f * BIASF - 2.f * __uint_as_float(a2 & 0xFFFFFFC0u);
      const uint32 c1 = cb_ + ((a1 & 60u) >> 2) * 128u + ((a1 & 3u) << 4);
      const uint32 c2 = cb_ + ((a2 & 60u) >> 2) * 128u + ((a2 & 3u) << 4);
      bpi[i][r] = c1 | (c2 << 16);
    }

  // cross-lane top-2 merge within 16-lane column groups (float-domain, unchanged)
#pragma unroll
  for (int m = 1; m <= 8; m <<= 1) {
#pragma unroll
    for (int i = 0; i < 4; ++i)
#pragma unroll
      for (int r = 0; r < 4; ++r) {
        const float ov1 = __shfl_xor(bv1[i][r], m, 64);
        const float ov2 = __shfl_xor(bv2[i][r], m, 64);
        const uint32 op = (uint32)__shfl_xor((int)bpi[i][r], m, 64);
        const uint32 ai1 = bpi[i][r] & 0xFFFFu, oi1 = op & 0xFFFFu;
        const bool ol = (ov1 < bv1[i][r]) || (ov1 == bv1[i][r] && oi1 < ai1);
        const float w1 = ol ? ov1 : bv1[i][r];
        const uint32 wi1 = ol ? oi1 : ai1;
        const float w2 = ol ? ov2 : bv2[i][r];
        const uint32 wi2 = ol ? (op >> 16) : (bpi[i][r] >> 16);
        const float l1 = ol ? bv1[i][r] : ov1;
        const uint32 li1 = ol ? ai1 : oi1;
        const bool s2 = (l1 < w2) || (l1 == w2 && li1 < wi2);
        bv1[i][r] = w1;
        bv2[i][r] = s2 ? l1 : w2;
        bpi[i][r] = wi1 | ((s2 ? li1 : wi2) << 16);
      }
  }
  if (l15 == 0) {
    const int slice = c * 4 + wc;
#pragma unroll
    for (int i = 0; i < 4; ++i)
#pragma unroll
      for (int r = 0; r < 4; ++r) {
        const int row = row0 + wr * 64 + i * 16 + lg * 4 + r;
        pt[(size_t)slice * NZ + row] =
            make_float4(bv1[i][r], bv2[i][r], __uint_as_float(bpi[i][r]), 0.f);
      }
  }
}

// ---------------------------------------------------------------- combine + exact fixup + quantize + loss
// 16 slices (lane&15 groups), 32 candidates. z2 computed inline from zv
// (same op order as the old prep: 4 products, pairwise adds, same butterfly).
__global__ void combine_kernel(const float* __restrict__ z, const float* __restrict__ emb,
                               const float* __restrict__ e2,
                               const float4* __restrict__ pt, float* __restrict__ oidx_f,
                               int* __restrict__ oidx_i, float* __restrict__ oq,
                               float* __restrict__ oloss) {
  const int row = blockIdx.x * 4 + (threadIdx.x >> 6);
  const int lane = threadIdx.x & 63;
  const int wid = threadIdx.x >> 6;
  const float4 p = pt[(size_t)(lane & 15) * NZ + row];
  const float v1 = p.x, v2 = p.y;
  const uint32 pk = __float_as_uint(p.z);
  float m = v1;
#pragma unroll
  for (int s = 1; s <= 8; s <<= 1) m = fminf(m, __shfl_xor(m, s, 64));

  const float4 zv = *reinterpret_cast<const float4*>(z + (size_t)row * DD + lane * 4);
  float z2r = (zv.x * zv.x + zv.y * zv.y) + (zv.z * zv.z + zv.w * zv.w);
  z2r = wave_reduce_sum(z2r);
  float bestd = 3.4e38f;
  int besti = KE;
#pragma unroll 1
  for (int cnum = 0; cnum < 32; ++cnum) {
    const int src = (lane & 48) | (cnum >> 1);
    const float vc = __shfl((cnum & 1) ? v2 : v1, src, 64);
    const uint32 pkc = (uint32)__shfl((int)pk, src, 64);
    const int idxc = (cnum & 1) ? (int)(pkc >> 16) : (int)(pkc & 0xFFFFu);
    if (vc < m + THR_GAP) {
      const float4 ev = *reinterpret_cast<const float4*>(emb + (size_t)idxc * DD + lane * 4);
      float s = (zv.x * ev.x + zv.y * ev.y) + (zv.z * ev.z + zv.w * ev.w);
      s = wave_reduce_sum(s);
      const float d = (z2r - 2.f * s) + e2[idxc];
      if (d < bestd || (d == bestd && idxc < besti)) { bestd = d; besti = idxc; }
    }
  }
  if (lane == 0) {
    oidx_f[row] = (float)besti;
    oidx_i[row] = besti;
  }
  // fused quantize + loss (quantized_st == emb[besti] numerically)
  const float4 qv = *reinterpret_cast<const float4*>(emb + (size_t)besti * DD + lane * 4);
  *reinterpret_cast<float4*>(oq + (size_t)row * DD + lane * 4) = qv;
  const float dx = zv.x - qv.x, dy = zv.y - qv.y, dz = zv.z - qv.z, dw = zv.w - qv.w;
  float s = (dx * dx + dy * dy) + (dz * dz + dw * dw);
  s = wave_reduce_sum(s);
  __shared__ float red[4];
  if (lane == 0) red[wid] = s;
  __syncthreads();
  if (threadIdx.x == 0) {
    const float t = (red[0] + red[1]) + (red[2] + red[3]);
    atomicAdd(oloss, t * (1.25f / ((float)NZ * (float)DD)));
  }
}

// ---------------------------------------------------------------- per-code EMA (8 codes/block)
__global__ void perk_kernel(const float* __restrict__ z, const float* __restrict__ ema_cs,
                            const float* __restrict__ ema_es, const int* __restrict__ usage,
                            const int* __restrict__ idx, const float* __restrict__ sema,
                            float* __restrict__ o_emb, float* __restrict__ o_cs,
                            float* __restrict__ o_es, float* __restrict__ o_us) {
  const int k0 = blockIdx.x * 8;
  const int tid = threadIdx.x;
  __shared__ int cnt;
  __shared__ int cnt8[8];
  __shared__ int stot[8];
  __shared__ int rows[2048];
  float acc[8];
#pragma unroll
  for (int q = 0; q < 8; ++q) acc[q] = 0.f;
  if (tid < 8) stot[tid] = 0;
  for (int base = 0; base < NZ; base += 2048) {
    if (tid == 0) cnt = 0;
    if (tid < 8) cnt8[tid] = 0;
    __syncthreads();
#pragma unroll
    for (int t = 0; t < 2048; t += 256) {
      const int r = base + t + tid;
      const int q = idx[r] - k0;
      if ((unsigned)q < 8u) {
        rows[atomicAdd(&cnt, 1)] = (r << 3) | q;
        atomicAdd(&cnt8[q], 1);
      }
    }
    __syncthreads();
    const int cq = cnt;
    if (tid < 8) stot[tid] += cnt8[tid];
    for (int m = 0; m < cq; ++m) {
      const int rr = rows[m];
      const float v = z[(size_t)(rr >> 3) * DD + tid];
      const int q = rr & 7;
#pragma unroll
      for (int qq = 0; qq < 8; ++qq)
        if (qq == q) acc[qq] += v;
    }
    __syncthreads();
  }
  const float n = 0.99f * sema[0] + 0.01f * (float)NZ;
  const float dn = n + (float)KE * 1e-5f;
#pragma unroll
  for (int q = 0; q < 8; ++q) {
    const float ncs = 0.99f * ema_cs[k0 + q] + 0.01f * (float)stot[q];
    const float nes = 0.99f * ema_es[(size_t)(k0 + q) * DD + tid] + 0.01f * acc[q];
    o_es[(size_t)(k0 + q) * DD + tid] = nes;
    o_emb[(size_t)(k0 + q) * DD + tid] = nes / ((ncs + 1e-5f) / dn * n);
  }
  if (tid < 8) {
    o_cs[k0 + tid] = 0.99f * ema_cs[k0 + tid] + 0.01f * (float)stot[tid];
    o_us[k0 + tid] = (float)(usage[k0 + tid] + stot[tid]);
  }
}

// ---------------------------------------------------------------- launch

extern "C" void kernel_launch(void* const* d_in, const int* in_sizes, int n_in,
                              void* d_out, int out_size, void* d_ws, size_t ws_size,
                              hipStream_t stream) {
  const float* z = (const float*)d_in[0];
  const float* emb = (const float*)d_in[1];
  const float* ema_cs = (const float*)d_in[2];
  const float* ema_es = (const float*)d_in[3];
  const int* usage = (const int*)d_in[4];

  float* out = (float*)d_out;
  float* o_idx = out;
  float* o_q = o_idx + NZ;
  float* o_loss = o_q + (size_t)NZ * DD;
  float* o_emb = o_loss + 1;
  float* o_cs = o_emb + (size_t)KE * DD;
  float* o_es = o_cs + KE;
  float* o_us = o_es + (size_t)KE * DD;

  char* w = (char*)d_ws;
  size_t off = 0;
  auto alloc = [&](size_t bytes) -> char* {
    char* r = w + off;
    off = (off + bytes + 255) & ~(size_t)255;
    return r;
  };
  float* ws_e2 = (float*)alloc(KE * 4);
  float* ws_sema = (float*)alloc(256);
  int* ws_idx = (int*)alloc(NZ * 4);
  float4* ws_pt = (float4*)alloc((size_t)NSLICE * NZ * 16);
  unsigned short* z_f16 = (unsigned short*)alloc((size_t)NZ * DD * 2);
  unsigned short* e_f16 = (unsigned short*)alloc((size_t)KE * DD * 2);
  (void)ws_size;

  prep_kernel<<<(KE / 4) + (NZ / 4) + 1, 256, 0, stream>>>(emb, e_f16, ws_e2, z, z_f16,
                                                           ema_cs, ws_sema, o_loss);

  mfma_argmin_kernel<<<(NZ / 128) * NCHUNK, 512, 0, stream>>>(z_f16, e_f16, ws_e2, ws_pt);
  combine_kernel<<<NZ / 4, 256, 0, stream>>>(z, emb, ws_e2, ws_pt, o_idx, ws_idx,
                                             o_q, o_loss);
  perk_kernel<<<KE / 8, 256, 0, stream>>>(z, ema_cs, ema_es, usage, ws_idx, ws_sema,
                                          o_emb, o_cs, o_es, o_us);
}

// Round 17
// 340.405 us; speedup vs baseline: 1.0205x; 1.0079x over previous
//
#include <hip/hip_runtime.h>

#define NZ 32768
#define KE 8192
#define DD 256
#define NCHUNK 4
#define CH (KE / NCHUNK)     // 2048 codes per chunk
#define NSLICE (NCHUNK * 4)  // 16 partial slices (4 wc quarters per chunk)
#define ITERS ((CH / 128) * 8)
#define THR_GAP 0.05f
#define BIASF 128.0f

typedef __attribute__((ext_vector_type(8))) _Float16 f16x8;
typedef __attribute__((ext_vector_type(4))) float f32x4;
typedef unsigned int uint32;

// ---------------------------------------------------------------- utilities

__device__ __forceinline__ float wave_reduce_sum(float v) {
#pragma unroll
  for (int m = 32; m >= 1; m >>= 1) v += __shfl_xor(v, m, 64);
  return v;
}

// ---------------------------------------------------------------- fused prologue (r29, proven):
// emb fp32->fp16 + row-square; z fp32->fp16; sum(ema_cluster_size); o_loss zero.
__global__ void prep_kernel(const float* __restrict__ emb, unsigned short* __restrict__ e_dst,
                            float* __restrict__ e_sq, const float* __restrict__ z,
                            unsigned short* __restrict__ z_dst,
                            const float* __restrict__ ema_cs, float* __restrict__ sema_out,
                            float* __restrict__ o_loss) {
  const int gb = blockIdx.x;
  if (gb < KE / 4) {
    const int row = gb * 4 + (threadIdx.x >> 6);
    const int lane = threadIdx.x & 63;
    const float4 v = *reinterpret_cast<const float4*>(emb + (size_t)row * DD + lane * 4);
    alignas(8) _Float16 hv[4] = {(_Float16)v.x, (_Float16)v.y, (_Float16)v.z, (_Float16)v.w};
    *reinterpret_cast<uint2*>(e_dst + (size_t)row * DD + lane * 4) =
        *reinterpret_cast<const uint2*>(hv);
    float s = (v.x * v.x + v.y * v.y) + (v.z * v.z + v.w * v.w);
    s = wave_reduce_sum(s);
    if (lane == 0) e_sq[row] = s;
  } else if (gb < (KE / 4) + (NZ / 4)) {
    const int row = (gb - KE / 4) * 4 + (threadIdx.x >> 6);
    const int lane = threadIdx.x & 63;
    const float4 v = *reinterpret_cast<const float4*>(z + (size_t)row * DD + lane * 4);
    alignas(8) _Float16 hv[4] = {(_Float16)v.x, (_Float16)v.y, (_Float16)v.z, (_Float16)v.w};
    *reinterpret_cast<uint2*>(z_dst + (size_t)row * DD + lane * 4) =
        *reinterpret_cast<const uint2*>(hv);
  } else {
    __shared__ float red[256];
    float s = 0.f;
    for (int i = threadIdx.x; i < KE; i += 256) s += ema_cs[i];
    red[threadIdx.x] = s;
    __syncthreads();
    for (int off = 128; off >= 1; off >>= 1) {
      if (threadIdx.x < off) red[threadIdx.x] += red[threadIdx.x + off];
      __syncthreads();
    }
    if (threadIdx.x == 0) {
      sema_out[0] = red[0];
      o_loss[0] = 0.f;
    }
  }
}

// ---------------------------------------------------------------- MFMA argmin GEMM (r29/r27 verbatim, proven 181.5 us)
// f16 A staged from z_f16, counted-vmcnt DMA B staging (16 bufs, 4 groups;
// window w computes group w&3 while DMA-staging window w+2; barrier =
// vmcnt(4) + s_barrier + sched_barrier(0)), e2/BIAS folded into acc init,
// branchless packed-key MAX top-2.

#define LSTR 32
#define NWIN (ITERS / 4)  // 32 windows of 4 K-steps

// A staging overlay: slice ki occupies exactly ldsB[ki] (128 rows x 32 shorts)
#define LDSA(ki, r) (&ldsB[ki][r][0])

// one global_load_lds per wave per step: 16 rows x 64B, linear LDS dest,
// pre-swizzled global source.
#define STAGEB(buf, itv)                                                        \
  {                                                                             \
    const int kb_ = ((itv) & 7) * 32;                                           \
    const size_t bo_ = (size_t)((itv) >> 3) * 128 * DD + kb_;                   \
    __builtin_amdgcn_global_load_lds((const uint32*)(ef + bsw + bo_),           \
                                     (uint32*)&ldsB[buf][wid * 16][0], 16, 0, 0); \
  }

// stage window ws (4 steps) into buf group SG (literal)
#define STAGEW(SG, ws)                                                          \
  {                                                                             \
    const int s0_ = (ws) * 4;                                                   \
    STAGEB((SG)*4 + 0, s0_ + 0)                                                 \
    STAGEB((SG)*4 + 1, s0_ + 1)                                                 \
    STAGEB((SG)*4 + 2, s0_ + 2)                                                 \
    STAGEB((SG)*4 + 3, s0_ + 3)                                                 \
  }

#define VBAR4                                                  \
  asm volatile("s_waitcnt vmcnt(4)" ::: "memory");             \
  __builtin_amdgcn_s_barrier();                                \
  __builtin_amdgcn_sched_barrier(0);

#define VBAR0                                                  \
  asm volatile("s_waitcnt vmcnt(0)" ::: "memory");             \
  __builtin_amdgcn_s_barrier();                                \
  __builtin_amdgcn_sched_barrier(0);

__launch_bounds__(512, 1)
__global__ void mfma_argmin_kernel(const unsigned short* __restrict__ zf,
                                   const unsigned short* __restrict__ ef,
                                   const float* __restrict__ e2,
                                   float4* __restrict__ pt) {
  __shared__ unsigned short ldsB[16][128][LSTR];  // 131072 B: 16 B-bufs; 0..7 double as A staging
  __shared__ float ldsE2[CH];                     // 8192 B: 128 - e2/2, pre-transformed
  const int bid = blockIdx.x;
  const int c = (bid & 7) >> 1;                    // chunk 0..3 (2 XCDs/chunk)
  const int mblk = ((bid >> 3) << 1) | (bid & 1);  // 0..255
  const int row0 = mblk * 128;
  const int cbase = c * CH;
  const int tid = threadIdx.x;
  const int wid = tid >> 6, lane = tid & 63;
  const int wr = wid >> 2, wc = wid & 3;           // 2 x 4 wave grid
  const int lg = lane >> 4, l15 = lane & 15;

  const int ur = tid >> 2;                         // 0..127
  const int usw = (((tid & 3) ^ ((ur >> 1) & 3)) << 3);
  const int csw = ((lg ^ ((l15 >> 1) & 3)) << 3);
  const size_t aoff0 = (size_t)(row0 + ur) * DD + (tid & 3) * 8;
  // B DMA source: row = ur, source chunk = (lane&3) ^ ((lane>>3)&3)
  const size_t bsw = (size_t)(cbase + ur) * DD + ((lane & 3) ^ ((lane >> 3) & 3)) * 8;

  // packed top-2 MAX trackers: key = (float_bits(z.e - e2/2 + 128) & ~63) | meta
  uint32 k1[4][4], k2[4][4];
#pragma unroll
  for (int i = 0; i < 4; ++i)
#pragma unroll
    for (int r = 0; r < 4; ++r) { k1[i][r] = 0u; k2[i][r] = 0u; }

  f32x4 acc[4][2];
  f16x8 areg[8][4];  // 128 VGPR: this wave's full A panel (64 rows x D=256)

  // prologue: stage e2 (pre-transformed) + A into LDS
  for (int i = tid; i < CH; i += 512) ldsE2[i] = BIASF - 0.5f * e2[cbase + i];
#pragma unroll
  for (int ki = 0; ki < 8; ++ki) {
    const uint4 va0 = *reinterpret_cast<const uint4*>(zf + aoff0 + ki * 32);
    *reinterpret_cast<uint4*>(LDSA(ki, ur) + usw) = va0;
  }
  __syncthreads();
  // A fragments -> registers
#pragma unroll
  for (int ki = 0; ki < 8; ++ki)
#pragma unroll
    for (int x = 0; x < 4; ++x)
      areg[ki][x] =
          *reinterpret_cast<const f16x8*>(LDSA(ki, wr * 64 + x * 16 + l15) + csw);
  __syncthreads();  // all waves' areg reads complete before DMA overwrites region
  // DMA windows 0,1 -> groups 0,1; vmcnt(4) completes window 0
  STAGEW(0, 0)
  STAGEW(1, 1)
  VBAR4

#define COMPUTE(buf, kil, tl)                                                           \
  {                                                                                     \
    if ((kil) == 0) {                                                                   \
      const int e2o_ = ((tl) << 7) + wc * 32 + l15;                                     \
      const float e0_ = ldsE2[e2o_];                                                    \
      const float e1_ = ldsE2[e2o_ + 16];                                               \
      _Pragma("unroll") for (int i = 0; i < 4; ++i) {                                   \
        acc[i][0] = (f32x4)(e0_);                                                       \
        acc[i][1] = (f32x4)(e1_);                                                       \
      }                                                                                 \
    }                                                                                   \
    f16x8 bh[2];                                                                        \
    _Pragma("unroll") for (int x = 0; x < 2; ++x)                                       \
      bh[x] = *reinterpret_cast<const f16x8*>(&ldsB[buf][wc * 32 + x * 16 + l15][csw]); \
    _Pragma("unroll") for (int i = 0; i < 4; ++i)                                       \
        _Pragma("unroll") for (int j = 0; j < 2; ++j)                                   \
            acc[i][j] = __builtin_amdgcn_mfma_f32_16x16x32_f16(areg[kil][i], bh[j], acc[i][j], 0, 0, 0); \
    if ((kil) == 7) {                                                                   \
      const uint32 tb_ = (uint32)((tl) << 2);                                           \
      _Pragma("unroll") for (int j = 0; j < 2; ++j) {                                   \
        const uint32 meta = tb_ | (uint32)j;                                            \
        _Pragma("unroll") for (int i = 0; i < 4; ++i)                                   \
            _Pragma("unroll") for (int r = 0; r < 4; ++r) {                             \
          const uint32 key = (__float_as_uint(acc[i][j][r]) & 0xFFFFFFC0u) | meta;      \
          const uint32 t = min(k1[i][r], key);                                          \
          k1[i][r] = max(k1[i][r], key);                                                \
          k2[i][r] = max(k2[i][r], t);                                                  \
        }                                                                               \
      }                                                                                 \
    }                                                                                   \
  }

// window wv: stage window wv+2 into group SG, compute group G, counted barrier.
// G = wv&3, SG = (wv+2)&3, P = wv&1 (all passed as literals); tile = wv>>1.
#define WINDOW(G, SG, wv, P)                                                \
  STAGEW(SG, (wv) + 2)                                                      \
  {                                                                         \
    const int tl_ = (wv) >> 1;                                              \
    COMPUTE((G)*4 + 0, (P)*4 + 0, tl_)                                      \
    COMPUTE((G)*4 + 1, (P)*4 + 1, tl_)                                      \
    COMPUTE((G)*4 + 2, (P)*4 + 2, tl_)                                      \
    COMPUTE((G)*4 + 3, (P)*4 + 3, tl_)                                      \
  }                                                                         \
  VBAR4

  // main loop: windows 0..27 (stages up to window 29)
  for (int W = 0; W < 28; W += 4) {
    WINDOW(0, 2, W + 0, 0)
    WINDOW(1, 3, W + 1, 1)
    WINDOW(2, 0, W + 2, 0)
    WINDOW(3, 1, W + 3, 1)
  }
  // windows 28,29: stage windows 30,31
  WINDOW(0, 2, 28, 0)
  WINDOW(1, 3, 29, 1)
  // window 30 (group 2, tile 15, ki 0..3): no stage; full drain for window 31
  COMPUTE(8, 0, 15)
  COMPUTE(9, 1, 15)
  COMPUTE(10, 2, 15)
  COMPUTE(11, 3, 15)
  VBAR0
  // window 31 (group 3, tile 15, ki 4..7)
  COMPUTE(12, 4, 15)
  COMPUTE(13, 5, 15)
  COMPUTE(14, 6, 15)
  COMPUTE(15, 7, 15)

  // decode packed MAX-keys back to (float distance value, 16-bit code) pairs:
  // tracked q = z.e - e2/2 + 128 ; v = e2 - 2 z.e = 256 - 2q
  float bv1[4][4], bv2[4][4];
  uint32 bpi[4][4];
  const uint32 cb_ = (uint32)(cbase + wc * 32 + l15);
#pragma unroll
  for (int i = 0; i < 4; ++i)
#pragma unroll
    for (int r = 0; r < 4; ++r) {
      const uint32 a1 = k1[i][r], a2 = k2[i][r];
      bv1[i][r] = 2.f * BIASF - 2.f * __uint_as_float(a1 & 0xFFFFFFC0u);
      bv2[i][r] = 2.f * BIASF - 2.f * __uint_as_float(a2 & 0xFFFFFFC0u);
      const uint32 c1 = cb_ + ((a1 & 60u) >> 2) * 128u + ((a1 & 3u) << 4);
      const uint32 c2 = cb_ + ((a2 & 60u) >> 2) * 128u + ((a2 & 3u) << 4);
      bpi[i][r] = c1 | (c2 << 16);
    }

  // cross-lane top-2 merge within 16-lane column groups (float-domain, unchanged)
#pragma unroll
  for (int m = 1; m <= 8; m <<= 1) {
#pragma unroll
    for (int i = 0; i < 4; ++i)
#pragma unroll
      for (int r = 0; r < 4; ++r) {
        const float ov1 = __shfl_xor(bv1[i][r], m, 64);
        const float ov2 = __shfl_xor(bv2[i][r], m, 64);
        const uint32 op = (uint32)__shfl_xor((int)bpi[i][r], m, 64);
        const uint32 ai1 = bpi[i][r] & 0xFFFFu, oi1 = op & 0xFFFFu;
        const bool ol = (ov1 < bv1[i][r]) || (ov1 == bv1[i][r] && oi1 < ai1);
        const float w1 = ol ? ov1 : bv1[i][r];
        const uint32 wi1 = ol ? oi1 : ai1;
        const float w2 = ol ? ov2 : bv2[i][r];
        const uint32 wi2 = ol ? (op >> 16) : (bpi[i][r] >> 16);
        const float l1 = ol ? bv1[i][r] : ov1;
        const uint32 li1 = ol ? ai1 : oi1;
        const bool s2 = (l1 < w2) || (l1 == w2 && li1 < wi2);
        bv1[i][r] = w1;
        bv2[i][r] = s2 ? l1 : w2;
        bpi[i][r] = wi1 | ((s2 ? li1 : wi2) << 16);
      }
  }
  if (l15 == 0) {
    const int slice = c * 4 + wc;
#pragma unroll
    for (int i = 0; i < 4; ++i)
#pragma unroll
      for (int r = 0; r < 4; ++r) {
        const int row = row0 + wr * 64 + i * 16 + lg * 4 + r;
        pt[(size_t)slice * NZ + row] =
            make_float4(bv1[i][r], bv2[i][r], __uint_as_float(bpi[i][r]), 0.f);
      }
  }
}

// ---------------------------------------------------------------- combine + exact fixup + quantize + loss
// r30: BALLOT-PRUNED candidate loop. The old fixed 32-iteration scan spent
// ~280 VALU/wave shuffle-extracting every candidate though typically only
// 1-4 pass the GAP test. All four 16-lane groups hold identical slice data,
// so __ballot(v < m+GAP) is group-replicated; take bits 0..15 (wave-uniform)
// and iterate only set bits (ctz + clear-lowest). Selection criterion is the
// unchanged lexicographic (d, idx) min -- order-independent, so besti is
// identical to the serial scan's.
__global__ void combine_kernel(const float* __restrict__ z, const float* __restrict__ emb,
                               const float* __restrict__ e2,
                               const float4* __restrict__ pt, float* __restrict__ oidx_f,
                               int* __restrict__ oidx_i, float* __restrict__ oq,
                               float* __restrict__ oloss) {
  const int row = blockIdx.x * 4 + (threadIdx.x >> 6);
  const int lane = threadIdx.x & 63;
  const int wid = threadIdx.x >> 6;
  const float4 p = pt[(size_t)(lane & 15) * NZ + row];
  const float v1 = p.x, v2 = p.y;
  const uint32 pk = __float_as_uint(p.z);
  float m = v1;
#pragma unroll
  for (int s = 1; s <= 8; s <<= 1) m = fminf(m, __shfl_xor(m, s, 64));
  const float thr = m + THR_GAP;
  const unsigned long long b1 = __ballot(v1 < thr) & 0xFFFFull;
  const unsigned long long b2 = __ballot(v2 < thr) & 0xFFFFull;

  const float4 zv = *reinterpret_cast<const float4*>(z + (size_t)row * DD + lane * 4);
  float z2r = (zv.x * zv.x + zv.y * zv.y) + (zv.z * zv.z + zv.w * zv.w);
  z2r = wave_reduce_sum(z2r);
  float bestd = 3.4e38f;
  int besti = KE;
  for (unsigned long long mm = b1; mm; mm &= mm - 1) {
    const int l = (int)__builtin_ctzll(mm);
    const uint32 pkc = (uint32)__shfl((int)pk, l, 64);
    const int idxc = (int)(pkc & 0xFFFFu);
    const float4 ev = *reinterpret_cast<const float4*>(emb + (size_t)idxc * DD + lane * 4);
    float s = (zv.x * ev.x + zv.y * ev.y) + (zv.z * ev.z + zv.w * ev.w);
    s = wave_reduce_sum(s);
    const float d = (z2r - 2.f * s) + e2[idxc];
    if (d < bestd || (d == bestd && idxc < besti)) { bestd = d; besti = idxc; }
  }
  for (unsigned long long mm = b2; mm; mm &= mm - 1) {
    const int l = (int)__builtin_ctzll(mm);
    const uint32 pkc = (uint32)__shfl((int)pk, l, 64);
    const int idxc = (int)(pkc >> 16);
    const float4 ev = *reinterpret_cast<const float4*>(emb + (size_t)idxc * DD + lane * 4);
    float s = (zv.x * ev.x + zv.y * ev.y) + (zv.z * ev.z + zv.w * ev.w);
    s = wave_reduce_sum(s);
    const float d = (z2r - 2.f * s) + e2[idxc];
    if (d < bestd || (d == bestd && idxc < besti)) { bestd = d; besti = idxc; }
  }
  if (lane == 0) {
    oidx_f[row] = (float)besti;
    oidx_i[row] = besti;
  }
  // fused quantize + loss (quantized_st == emb[besti] numerically)
  const float4 qv = *reinterpret_cast<const float4*>(emb + (size_t)besti * DD + lane * 4);
  *reinterpret_cast<float4*>(oq + (size_t)row * DD + lane * 4) = qv;
  const float dx = zv.x - qv.x, dy = zv.y - qv.y, dz = zv.z - qv.z, dw = zv.w - qv.w;
  float s = (dx * dx + dy * dy) + (dz * dz + dw * dw);
  s = wave_reduce_sum(s);
  __shared__ float red[4];
  if (lane == 0) red[wid] = s;
  __syncthreads();
  if (threadIdx.x == 0) {
    const float t = (red[0] + red[1]) + (red[2] + red[3]);
    atomicAdd(oloss, t * (1.25f / ((float)NZ * (float)DD)));
  }
}

// ---------------------------------------------------------------- per-code EMA (8 codes/block)
__global__ void perk_kernel(const float* __restrict__ z, const float* __restrict__ ema_cs,
                            const float* __restrict__ ema_es, const int* __restrict__ usage,
                            const int* __restrict__ idx, const float* __restrict__ sema,
                            float* __restrict__ o_emb, float* __restrict__ o_cs,
                            float* __restrict__ o_es, float* __restrict__ o_us) {
  const int k0 = blockIdx.x * 8;
  const int tid = threadIdx.x;
  __shared__ int cnt;
  __shared__ int cnt8[8];
  __shared__ int stot[8];
  __shared__ int rows[2048];
  float acc[8];
#pragma unroll
  for (int q = 0; q < 8; ++q) acc[q] = 0.f;
  if (tid < 8) stot[tid] = 0;
  for (int base = 0; base < NZ; base += 2048) {
    if (tid == 0) cnt = 0;
    if (tid < 8) cnt8[tid] = 0;
    __syncthreads();
#pragma unroll
    for (int t = 0; t < 2048; t += 256) {
      const int r = base + t + tid;
      const int q = idx[r] - k0;
      if ((unsigned)q < 8u) {
        rows[atomicAdd(&cnt, 1)] = (r << 3) | q;
        atomicAdd(&cnt8[q], 1);
      }
    }
    __syncthreads();
    const int cq = cnt;
    if (tid < 8) stot[tid] += cnt8[tid];
    for (int m = 0; m < cq; ++m) {
      const int rr = rows[m];
      const float v = z[(size_t)(rr >> 3) * DD + tid];
      const int q = rr & 7;
#pragma unroll
      for (int qq = 0; qq < 8; ++qq)
        if (qq == q) acc[qq] += v;
    }
    __syncthreads();
  }
  const float n = 0.99f * sema[0] + 0.01f * (float)NZ;
  const float dn = n + (float)KE * 1e-5f;
#pragma unroll
  for (int q = 0; q < 8; ++q) {
    const float ncs = 0.99f * ema_cs[k0 + q] + 0.01f * (float)stot[q];
    const float nes = 0.99f * ema_es[(size_t)(k0 + q) * DD + tid] + 0.01f * acc[q];
    o_es[(size_t)(k0 + q) * DD + tid] = nes;
    o_emb[(size_t)(k0 + q) * DD + tid] = nes / ((ncs + 1e-5f) / dn * n);
  }
  if (tid < 8) {
    o_cs[k0 + tid] = 0.99f * ema_cs[k0 + tid] + 0.01f * (float)stot[tid];
    o_us[k0 + tid] = (float)(usage[k0 + tid] + stot[tid]);
  }
}

// ---------------------------------------------------------------- launch

extern "C" void kernel_launch(void* const* d_in, const int* in_sizes, int n_in,
                              void* d_out, int out_size, void* d_ws, size_t ws_size,
                              hipStream_t stream) {
  const float* z = (const float*)d_in[0];
  const float* emb = (const float*)d_in[1];
  const float* ema_cs = (const float*)d_in[2];
  const float* ema_es = (const float*)d_in[3];
  const int* usage = (const int*)d_in[4];

  float* out = (float*)d_out;
  float* o_idx = out;
  float* o_q = o_idx + NZ;
  float* o_loss = o_q + (size_t)NZ * DD;
  float* o_emb = o_loss + 1;
  float* o_cs = o_emb + (size_t)KE * DD;
  float* o_es = o_cs + KE;
  float* o_us = o_es + (size_t)KE * DD;

  char* w = (char*)d_ws;
  size_t off = 0;
  auto alloc = [&](size_t bytes) -> char* {
    char* r = w + off;
    off = (off + bytes + 255) & ~(size_t)255;
    return r;
  };
  float* ws_e2 = (float*)alloc(KE * 4);
  float* ws_sema = (float*)alloc(256);
  int* ws_idx = (int*)alloc(NZ * 4);
  float4* ws_pt = (float4*)alloc((size_t)NSLICE * NZ * 16);
  unsigned short* z_f16 = (unsigned short*)alloc((size_t)NZ * DD * 2);
  unsigned short* e_f16 = (unsigned short*)alloc((size_t)KE * DD * 2);
  (void)ws_size;

  prep_kernel<<<(KE / 4) + (NZ / 4) + 1, 256, 0, stream>>>(emb, e_f16, ws_e2, z, z_f16,
                                                           ema_cs, ws_sema, o_loss);

  mfma_argmin_kernel<<<(NZ / 128) * NCHUNK, 512, 0, stream>>>(z_f16, e_f16, ws_e2, ws_pt);
  combine_kernel<<<NZ / 4, 256, 0, stream>>>(z, emb, ws_e2, ws_pt, o_idx, ws_idx,
                                             o_q, o_loss);
  perk_kernel<<<KE / 8, 256, 0, stream>>>(z, ema_cs, ema_es, usage, ws_idx, ws_sema,
                                          o_emb, o_cs, o_es, o_us);
}